// Round 6
// baseline (80.431 us; speedup 1.0000x reference)
//
#include <hip/hip_runtime.h>

typedef float f32x4 __attribute__((ext_vector_type(4)));
typedef short s16x8 __attribute__((ext_vector_type(8)));
typedef unsigned short u16;
typedef unsigned short u16x8 __attribute__((ext_vector_type(8)));

__device__ __forceinline__ u16 f2bf(float f) {
  unsigned u = __builtin_bit_cast(unsigned, f);
  u += 0x7fffu + ((u >> 16) & 1u);   // RNE
  return (u16)(u >> 16);
}

__device__ __forceinline__ unsigned cvt_pk_bf16(float a, float b) {
  unsigned r;
  asm("v_cvt_pk_bf16_f32 %0, %1, %2" : "=v"(r) : "v"(a), "v"(b));
  return r;   // lo = bf16(a), hi = bf16(b), RNE
}

#define AS1 __attribute__((address_space(1)))
#define AS3 __attribute__((address_space(3)))
#define GLD16(g, l) __builtin_amdgcn_global_load_lds((const AS1 unsigned int*)(g), (AS3 unsigned int*)(l), 16, 0, 0)

// ---------------- Kernel 0: prepack W -> bf16, chunk-major, swizzled ----------------
__global__ __launch_bounds__(256) void prepack_w(
    const float* __restrict__ wq, const float* __restrict__ wk, const float* __restrict__ wv,
    u16* __restrict__ Wpk)
{
  const int d = blockIdx.x;          // 0..191
  const int t = threadIdx.x;         // kc = t>>3 (0..31), blk = t&7
  const int kc = t >> 3, blk = t & 7;
  const int key = (d >> 1) & 7;
  const float* src = (d < 64) ? (wq + (size_t)d * 2048)
                   : (d < 128) ? (wk + (size_t)(d - 64) * 2048)
                               : (wv + (size_t)(d - 128) * 2048);
  const float* s8 = src + kc * 64 + ((blk ^ key) << 3);
  u16x8 o;
#pragma unroll
  for (int j = 0; j < 8; ++j) o[j] = f2bf(s8[j]);
  *(u16x8*)(Wpk + ((size_t)(kc * 192 + d) << 6) + (blk << 3)) = o;
}

// ---------------- Kernel 1: fused QKV projection ----------------
// grid 256 (16 b x 16 ptile of 64), block 512 (8 waves).
// Even/odd k-groups: waves 0-3 compute even chunks, 4-7 odd chunks; each wave
// owns a 64p x 48d tile (m4 x n3 frags). All 512 threads stage every chunk:
// x (2 float4, 2 chunks ahead in regs), W (3 GLD16, 1 chunk ahead).
// Barrier = vmcnt(2) lgkmcnt(0): W(c+1) complete, x(c+2) stays in flight.
__global__ __launch_bounds__(512) void qkv_proj(
    const float* __restrict__ x, const u16* __restrict__ Wpk,
    const float* __restrict__ bq, const float* __restrict__ bk, const float* __restrict__ bv,
    u16* __restrict__ Qo, u16* __restrict__ Ko, u16* __restrict__ Vt)
{
  const int b   = blockIdx.x >> 4;
  const int p0  = (blockIdx.x & 15) * 64;
  const int tid = threadIdx.x;
  const int lane = tid & 63;
  const int wid  = tid >> 6;
  const int l15 = lane & 15, l4 = lane >> 4;
  const int cw  = wid & 3;    // d-quarter (48 rows)
  const int grp = wid >> 2;   // 0: even chunks, 1: odd chunks

  __shared__ __align__(16) char smem[65536];
  // lA slot s: smem + s*8192          (64p x 64k bf16, swizzled 16B blocks)
  // lB slot s: smem + 16384 + s*24576 (192d x 64k bf16, swizzled content)

  // x staging mapping: thread covers k-quad kbq (4 k's), row-pair rp, 4 p-cols
  const int kbq = wid * 2 + (l4 >> 1);   // 0..15
  const int rp  = (l4 & 1) * 2;          // 0 or 2
  const int pc0 = l15 * 4;

  f32x4 acc[4][3];
#pragma unroll
  for (int m = 0; m < 4; ++m)
#pragma unroll
    for (int n = 0; n < 3; ++n) acc[m][n] = (f32x4)(0.0f);

  const float* xb = x + (size_t)b * 2048 * 1024 + p0 + pc0;
  float4 xr[2][2];

  auto xissue = [&](int c, int buf) {
    const float* g = xb + (size_t)(c * 64 + kbq * 4 + rp) * 1024;
    xr[buf][0] = *(const float4*)g;
    xr[buf][1] = *(const float4*)(g + 1024);
  };
  auto xwrite = [&](int c, int buf) {
    char* base = smem + (c & 1) * 8192;
#pragma unroll
    for (int col = 0; col < 4; ++col) {
      int p = pc0 + col;
      unsigned pk = cvt_pk_bf16(xr[buf][0][col], xr[buf][1][col]);
      char* dst = base + p * 128 + (((kbq >> 1) ^ ((p >> 1) & 7)) << 4)
                + (kbq & 1) * 8 + (rp >> 1) * 4;
      *(unsigned*)dst = pk;
    }
  };
  auto wissue = [&](int c) {
    const u16* g = Wpk + (size_t)c * 12288 + lane * 8;
    char* base = smem + 16384 + (c & 1) * 24576;
#pragma unroll
    for (int j = 0; j < 3; ++j) {
      int q = wid * 3 + j;               // 0..23, covers lB rows q*8..q*8+7
      GLD16(g + q * 512, base + q * 1024);
    }
  };
  auto domfma = [&](int slot) {
    const char* aB = smem + slot * 8192;
    const char* bB = smem + 16384 + slot * 24576;
#pragma unroll
    for (int ks = 0; ks < 2; ++ks) {
      s16x8 af[4], bfv[3];
#pragma unroll
      for (int m = 0; m < 4; ++m) {
        int p = m * 16 + l15;
        int swz = ((ks * 4 + l4) ^ ((p >> 1) & 7)) & 7;
        af[m] = *(const s16x8*)(aB + p * 128 + (swz << 4));
      }
#pragma unroll
      for (int n = 0; n < 3; ++n) {
        int d = cw * 48 + n * 16 + l15;
        int swz = ((ks * 4 + l4) ^ ((d >> 1) & 7)) & 7;
        bfv[n] = *(const s16x8*)(bB + d * 128 + (swz << 4));
      }
#pragma unroll
      for (int m = 0; m < 4; ++m)
#pragma unroll
        for (int n = 0; n < 3; ++n)
          acc[m][n] = __builtin_amdgcn_mfma_f32_16x16x32_bf16(af[m], bfv[n], acc[m][n], 0, 0, 0);
    }
  };

  // prologue: W(0), x(0), x(1) issued; wait W0+x0; write x(0)->lA[0]
  wissue(0);
  xissue(0, 0);
  xissue(1, 1);
  asm volatile("s_waitcnt vmcnt(2)" ::: "memory");
  __builtin_amdgcn_sched_barrier(0);
  xwrite(0, 0);
  asm volatile("s_waitcnt lgkmcnt(0)" ::: "memory");
  __builtin_amdgcn_sched_barrier(0);
  __builtin_amdgcn_s_barrier();
  __builtin_amdgcn_sched_barrier(0);

  for (int c = 0; c < 32; ++c) {
    if (c < 31) wissue(c + 1);
    if (c < 30) xissue(c + 2, c & 1);
    if (grp == (c & 1)) {
      __builtin_amdgcn_s_setprio(1);
      domfma(c & 1);
      __builtin_amdgcn_s_setprio(0);
    }
    if (c < 31) xwrite(c + 1, (c + 1) & 1);
    if (c < 30) asm volatile("s_waitcnt vmcnt(2) lgkmcnt(0)" ::: "memory");
    else        asm volatile("s_waitcnt vmcnt(0) lgkmcnt(0)" ::: "memory");
    __builtin_amdgcn_sched_barrier(0);
    __builtin_amdgcn_s_barrier();
    __builtin_amdgcn_sched_barrier(0);
  }

  // combine group1 partials into group0 via LDS (48KB, reuses staging space)
  if (grp == 1) {
#pragma unroll
    for (int m = 0; m < 4; ++m)
#pragma unroll
      for (int n = 0; n < 3; ++n)
        *(f32x4*)(smem + cw * 12288 + ((m * 3 + n) * 64 + lane) * 16) = acc[m][n];
  }
  asm volatile("s_waitcnt lgkmcnt(0)" ::: "memory");
  __builtin_amdgcn_s_barrier();
  if (grp == 0) {
#pragma unroll
    for (int m = 0; m < 4; ++m)
#pragma unroll
      for (int n = 0; n < 3; ++n)
        acc[m][n] += *(const f32x4*)(smem + cw * 12288 + ((m * 3 + n) * 64 + lane) * 16);

    // epilogue: bias + store. Q,K -> [b][p][64]; V -> [b][64][p]
#pragma unroll
    for (int n = 0; n < 3; ++n) {
      const int dg = cw * 48 + n * 16 + l15;
      const int wi = dg >> 6, dl = dg & 63;
      const float* bsrc = (wi == 0) ? bq : (wi == 1) ? bk : bv;
      const float bias = bsrc[dl];
#pragma unroll
      for (int m = 0; m < 4; ++m) {
        const int pl = m * 16 + l4 * 4;
        f32x4 a = acc[m][n];
        if (wi < 2) {
          u16* dst = (wi == 0 ? Qo : Ko) + ((size_t)b * 1024 + p0 + pl) * 64 + dl;
#pragma unroll
          for (int r = 0; r < 4; ++r) dst[(size_t)r * 64] = f2bf(a[r] + bias);
        } else {
          ushort4 hh;
          hh.x = f2bf(a[0] + bias); hh.y = f2bf(a[1] + bias);
          hh.z = f2bf(a[2] + bias); hh.w = f2bf(a[3] + bias);
          *(ushort4*)(Vt + ((size_t)b * 64 + dl) * 1024 + p0 + pl) = hh;
        }
      }
    }
  }
}

// ---------------- Kernel 2: flash attention (no-max softmax, KV-half split) ----------------
// grid 512 = b(16) x qtile(16) x half(2); block 256 (4 waves x 16 q-rows).
__global__ __launch_bounds__(256) void attn_kernel(
    const u16* __restrict__ Qg, const u16* __restrict__ Kg,
    const u16* __restrict__ Vg, float* __restrict__ Po, float* __restrict__ lp)
{
  const int bid = blockIdx.x;
  const int b  = bid >> 5;
  const int qt = (bid >> 1) & 15;
  const int h  = bid & 1;
  const int q0 = qt * 64;
  const int tid = threadIdx.x;
  const int lane = tid & 63;
  const int wid = tid >> 6;
  const int l15 = lane & 15, l4 = lane >> 4;
  const int qb = q0 + wid * 16;

  __shared__ __align__(16) u16 lK[2][128 * 64];   // swz: blk^=(row>>1)&7
  __shared__ __align__(16) u16 lV[2][64 * 128];   // swz: blk^=(row&7)<<1
  __shared__ __align__(16) u16 lP[4][16 * 128];   // swz: blk^=(row&7)<<1

  s16x8 qa[2];
#pragma unroll
  for (int ks = 0; ks < 2; ++ks)
    qa[ks] = *(const s16x8*)(Qg + ((size_t)b * 1024 + qb + l15) * 64 + ks * 32 + l4 * 8);

  float l_run[4];
  f32x4 oacc[4];
#pragma unroll
  for (int r = 0; r < 4; ++r) l_run[r] = 0.f;
#pragma unroll
  for (int n = 0; n < 4; ++n) oacc[n] = (f32x4)(0.0f);

  u16x8 kp[4], vp[4];
  auto load_kv = [&](int kc) {
    const int pk0 = kc * 128;
#pragma unroll
    for (int i = 0; i < 4; ++i) {
      int idx = tid + 256 * i;
      int row = idx >> 3, blk = idx & 7;
      kp[i] = *(const u16x8*)(Kg + ((size_t)b * 1024 + pk0 + row) * 64 + blk * 8);
      int vr = idx >> 4, vbk = idx & 15;
      vp[i] = *(const u16x8*)(Vg + ((size_t)b * 64 + vr) * 1024 + pk0 + vbk * 8);
    }
  };
  auto store_kv = [&](int buf) {
#pragma unroll
    for (int i = 0; i < 4; ++i) {
      int idx = tid + 256 * i;
      int row = idx >> 3, blk = idx & 7;
      *(u16x8*)(&lK[buf][0] + row * 64 + ((blk ^ ((row >> 1) & 7)) << 3)) = kp[i];
      int vr = idx >> 4, vbk = idx & 15;
      *(u16x8*)(&lV[buf][0] + vr * 128 + ((vbk ^ ((vr & 7) << 1)) << 3)) = vp[i];
    }
  };

  const int kc0 = h * 4;
  load_kv(kc0); store_kv(0); __syncthreads();

  const float CEXP = 0.0225422933f;   // log2(e)/64

  for (int ic = 0; ic < 4; ++ic) {
    const int cur = ic & 1;
    if (ic + 1 < 4) load_kv(kc0 + ic + 1);

    f32x4 sacc[8];
#pragma unroll
    for (int n = 0; n < 8; ++n) sacc[n] = (f32x4)(0.0f);
#pragma unroll
    for (int ks = 0; ks < 2; ++ks) {
#pragma unroll
      for (int n = 0; n < 8; ++n) {
        int row = n * 16 + l15;
        s16x8 kv = *(const s16x8*)(&lK[cur][0] + row * 64 +
                     (((ks * 4 + l4) ^ ((row >> 1) & 7)) << 3));
        sacc[n] = __builtin_amdgcn_mfma_f32_16x16x32_bf16(qa[ks], kv, sacc[n], 0, 0, 0);
      }
    }

#pragma unroll
    for (int r = 0; r < 4; ++r) {
      const int prow = l4 * 4 + r;
      float psum = 0.f;
#pragma unroll
      for (int n = 0; n < 8; ++n) {
        float pv = exp2f(sacc[n][r] * CEXP);
        psum += pv;
        int blk = (n * 2 + (l15 >> 3)) ^ ((prow & 7) << 1);
        lP[wid][prow * 128 + blk * 8 + (l15 & 7)] = f2bf(pv);
      }
      psum += __shfl_xor(psum, 1);
      psum += __shfl_xor(psum, 2);
      psum += __shfl_xor(psum, 4);
      psum += __shfl_xor(psum, 8);
      l_run[r] += psum;
    }

#pragma unroll
    for (int ks = 0; ks < 4; ++ks) {
      s16x8 pfr = *(const s16x8*)(&lP[wid][0] + l15 * 128 +
                    (((ks * 4 + l4) ^ ((l15 & 7) << 1)) << 3));
#pragma unroll
      for (int n = 0; n < 4; ++n) {
        int row = n * 16 + l15;
        s16x8 vv = *(const s16x8*)(&lV[cur][0] + row * 128 +
                     (((ks * 4 + l4) ^ ((row & 7) << 1)) << 3));
        oacc[n] = __builtin_amdgcn_mfma_f32_16x16x32_bf16(pfr, vv, oacc[n], 0, 0, 0);
      }
    }

    if (ic + 1 < 4) store_kv(cur ^ 1);
    __syncthreads();
  }

#pragma unroll
  for (int n = 0; n < 4; ++n) {
    const int d = n * 16 + l15;
    float4 o;
    o.x = oacc[n][0]; o.y = oacc[n][1]; o.z = oacc[n][2]; o.w = oacc[n][3];
    *(float4*)(Po + (((size_t)h * 16 + b) * 64 + d) * 1024 + q0 + wid * 16 + l4 * 4) = o;
  }
  if (l15 == 0) {
#pragma unroll
    for (int r = 0; r < 4; ++r)
      lp[((size_t)h * 16 + b) * 1024 + qb + l4 * 4 + r] = l_run[r];
  }
}

// ---------------- Kernel 3: merge halves ----------------
__global__ __launch_bounds__(256) void attn_merge(
    const float* __restrict__ Po, const float* __restrict__ lp, float* __restrict__ out)
{
  const int i = (blockIdx.x * 256 + threadIdx.x) * 4;
  float4 a = *(const float4*)(Po + i);
  float4 c = *(const float4*)(Po + 1048576 + i);
  const int b = i >> 16;
  const int p = i & 1023;
  const float* l0 = lp + b * 1024 + p;
  const float* l1 = lp + 16384 + b * 1024 + p;
  float4 o;
  o.x = (a.x + c.x) / (l0[0] + l1[0]);
  o.y = (a.y + c.y) / (l0[1] + l1[1]);
  o.z = (a.z + c.z) / (l0[2] + l1[2]);
  o.w = (a.w + c.w) / (l0[3] + l1[3]);
  *(float4*)(out + i) = o;
}

extern "C" void kernel_launch(void* const* d_in, const int* in_sizes, int n_in,
                              void* d_out, int out_size, void* d_ws, size_t ws_size,
                              hipStream_t stream) {
  const float* x  = (const float*)d_in[0];
  const float* wq = (const float*)d_in[1];
  const float* bq = (const float*)d_in[2];
  const float* wk = (const float*)d_in[3];
  const float* bk = (const float*)d_in[4];
  const float* wv = (const float*)d_in[5];
  const float* bv = (const float*)d_in[6];
  float* out = (float*)d_out;

  u16* Qo  = (u16*)d_ws;                              // [16][1024][64] bf16
  u16* Ko  = Qo + (size_t)16 * 1024 * 64;             // [16][1024][64] bf16
  u16* Vt  = Ko + (size_t)16 * 1024 * 64;             // [16][64][1024] bf16
  u16* Wpk = Vt + (size_t)16 * 1024 * 64;             // [32][192][64] bf16 prepacked
  float* Po = (float*)(Wpk + (size_t)32 * 192 * 64);  // [2][16][64][1024] f32 partial O
  float* lpart = Po + (size_t)2 * 16 * 64 * 1024;     // [2][16][1024] f32 partial l

  prepack_w<<<192, 256, 0, stream>>>(wq, wk, wv, Wpk);
  qkv_proj<<<256, 512, 0, stream>>>(x, Wpk, bq, bk, bv, Qo, Ko, Vt);
  attn_kernel<<<512, 256, 0, stream>>>(Qo, Ko, Vt, Po, lpart);
  attn_merge<<<1024, 256, 0, stream>>>(Po, lpart, out);
}

// Round 7
// 78.486 us; speedup vs baseline: 1.0248x; 1.0248x over previous
//
#include <hip/hip_runtime.h>

typedef float f32x4 __attribute__((ext_vector_type(4)));
typedef short s16x8 __attribute__((ext_vector_type(8)));
typedef unsigned short u16;
typedef unsigned short u16x8 __attribute__((ext_vector_type(8)));

__device__ __forceinline__ u16 f2bf(float f) {
  unsigned u = __builtin_bit_cast(unsigned, f);
  u += 0x7fffu + ((u >> 16) & 1u);   // RNE
  return (u16)(u >> 16);
}

__device__ __forceinline__ unsigned cvt_pk_bf16(float a, float b) {
  unsigned r;
  asm("v_cvt_pk_bf16_f32 %0, %1, %2" : "=v"(r) : "v"(a), "v"(b));
  return r;   // lo = bf16(a), hi = bf16(b), RNE
}

#define AS1 __attribute__((address_space(1)))
#define AS3 __attribute__((address_space(3)))
#define GLD16(g, l) __builtin_amdgcn_global_load_lds((const AS1 unsigned int*)(g), (AS3 unsigned int*)(l), 16, 0, 0)

// ---------------- Kernel 0: prepack W -> bf16, chunk-major, swizzled ----------------
__global__ __launch_bounds__(256) void prepack_w(
    const float* __restrict__ wq, const float* __restrict__ wk, const float* __restrict__ wv,
    u16* __restrict__ Wpk)
{
  const int d = blockIdx.x;          // 0..191
  const int t = threadIdx.x;         // kc = t>>3 (0..31), blk = t&7
  const int kc = t >> 3, blk = t & 7;
  const int key = (d >> 1) & 7;
  const float* src = (d < 64) ? (wq + (size_t)d * 2048)
                   : (d < 128) ? (wk + (size_t)(d - 64) * 2048)
                               : (wv + (size_t)(d - 128) * 2048);
  const float* s8 = src + kc * 64 + ((blk ^ key) << 3);
  u16x8 o;
#pragma unroll
  for (int j = 0; j < 8; ++j) o[j] = f2bf(s8[j]);
  *(u16x8*)(Wpk + ((size_t)(kc * 192 + d) << 6) + (blk << 3)) = o;
}

// ---------------- Kernel 1: fused QKV projection, d-split for occupancy ----------------
// grid 512 = b(16) x ptile(16) x dhalf(2); block 512 (8 waves); LDS 40KB -> 2 blocks/CU.
// Block tile: 64p x 96d, full K. Wave = 16p x 48d (wm=wid&3, wn=wid>>2), all compute.
// Waves 0-3 stage W (3 GLD16/chunk, 1 ahead, L2); waves 4-7 stage x (4-deep reg prefetch).
__global__ __launch_bounds__(512, 4) void qkv_proj(
    const float* __restrict__ x, const u16* __restrict__ Wpk,
    const float* __restrict__ bq, const float* __restrict__ bk, const float* __restrict__ bv,
    u16* __restrict__ Qo, u16* __restrict__ Ko, u16* __restrict__ Vt)
{
  const int b   = blockIdx.x >> 5;
  const int p0  = ((blockIdx.x >> 1) & 15) * 64;
  const int h   = blockIdx.x & 1;
  const int tid = threadIdx.x;
  const int lane = tid & 63;
  const int wid  = tid >> 6;
  const int l15 = lane & 15, l4 = lane >> 4;
  const int wm = wid & 3;     // p-sixteenth
  const int wn = wid >> 2;    // d-48-half of the 96
  const bool isW = (wid < 4);

  __shared__ __align__(16) char smem[40960];
  // lA slot s (s=0,1): smem + s*8192           (64p x 64k bf16, 16B-block XOR swz)
  // lB slot s:         smem + 16384 + s*12288  (96d x 64k bf16, content pre-swizzled)

  const int kbq = (wid - 4) * 4 + l4;   // x-waves: k-quad 0..15
  const int pc0 = l15 * 4;

  f32x4 acc[3];
#pragma unroll
  for (int n = 0; n < 3; ++n) acc[n] = (f32x4)(0.0f);

  const float* xb = x + (size_t)b * 2048 * 1024 + p0 + pc0;
  float4 X0[4], X1[4], X2[4], X3[4];

  auto xissue = [&](int c, float4 (&X)[4]) {
    const float* g = xb + (size_t)(c * 64 + kbq * 4) * 1024;
#pragma unroll
    for (int r = 0; r < 4; ++r) X[r] = *(const float4*)(g + r * 1024);
  };
  auto xwrite = [&](int c, float4 (&X)[4]) {
    char* base = smem + (c & 1) * 8192;
#pragma unroll
    for (int col = 0; col < 4; ++col) {
      int p = pc0 + col;
      unsigned lo = cvt_pk_bf16(X[0][col], X[1][col]);
      unsigned hi = cvt_pk_bf16(X[2][col], X[3][col]);
      int swz = ((kbq >> 1) ^ ((p >> 1) & 7)) & 7;
      *(uint2*)(base + p * 128 + (swz << 4) + (kbq & 1) * 8) = make_uint2(lo, hi);
    }
  };
  auto wissue = [&](int c) {
    const u16* g = Wpk + (size_t)c * 12288 + h * 6144 + lane * 8;
    char* base = smem + 16384 + (c & 1) * 12288;
#pragma unroll
    for (int j = 0; j < 3; ++j) {
      int q = wid * 3 + j;               // 0..11, rows q*8..q*8+7 of the 96
      GLD16(g + q * 512, base + q * 1024);
    }
  };
  auto domfma = [&](int slot) {
    const char* aB = smem + slot * 8192;
    const char* bB = smem + 16384 + slot * 12288;
#pragma unroll
    for (int ks = 0; ks < 2; ++ks) {
      const int p = wm * 16 + l15;
      s16x8 af = *(const s16x8*)(aB + p * 128 +
                   ((((ks * 4 + l4) ^ ((p >> 1) & 7)) & 7) << 4));
#pragma unroll
      for (int n = 0; n < 3; ++n) {
        const int dl = wn * 48 + n * 16 + l15;
        s16x8 bv_ = *(const s16x8*)(bB + dl * 128 +
                      ((((ks * 4 + l4) ^ ((dl >> 1) & 7)) & 7) << 4));
        acc[n] = __builtin_amdgcn_mfma_f32_16x16x32_bf16(af, bv_, acc[n], 0, 0, 0);
      }
    }
  };

#define BAR() do {                                                        \
    if (isW) asm volatile("s_waitcnt vmcnt(0)" ::: "memory");             \
    else     asm volatile("s_waitcnt lgkmcnt(0)" ::: "memory");           \
    __builtin_amdgcn_sched_barrier(0);                                    \
    __builtin_amdgcn_s_barrier();                                         \
    __builtin_amdgcn_sched_barrier(0);                                    \
  } while (0)

  // prologue: W(0) -> lB[0]; x(0..3) -> X0..X3; x(0) -> lA[0]
  if (isW) {
    wissue(0);
  } else {
    xissue(0, X0); xissue(1, X1); xissue(2, X2); xissue(3, X3);
    xwrite(0, X0);
  }
  BAR();

  for (int i = 0; i < 8; ++i) {
    const int c0 = i * 4;
    // chunk c0+0 (slot 0): issue x(c0+4)->X0, W(c0+1); write x(c0+1) from X1
    if (isW)              wissue(c0 + 1);
    else if (c0 + 4 < 32) xissue(c0 + 4, X0);
    __builtin_amdgcn_s_setprio(1); domfma(0); __builtin_amdgcn_s_setprio(0);
    if (!isW) xwrite(c0 + 1, X1);
    BAR();
    // chunk c0+1 (slot 1)
    if (isW)              wissue(c0 + 2);
    else if (c0 + 5 < 32) xissue(c0 + 5, X1);
    __builtin_amdgcn_s_setprio(1); domfma(1); __builtin_amdgcn_s_setprio(0);
    if (!isW) xwrite(c0 + 2, X2);
    BAR();
    // chunk c0+2 (slot 0)
    if (isW) { if (c0 + 3 < 32) wissue(c0 + 3); }
    else if (c0 + 6 < 32) xissue(c0 + 6, X2);
    __builtin_amdgcn_s_setprio(1); domfma(0); __builtin_amdgcn_s_setprio(0);
    if (!isW) xwrite(c0 + 3, X3);
    BAR();
    // chunk c0+3 (slot 1)
    if (isW) { if (c0 + 4 < 32) wissue(c0 + 4); }
    else if (c0 + 7 < 32) xissue(c0 + 7, X3);
    __builtin_amdgcn_s_setprio(1); domfma(1); __builtin_amdgcn_s_setprio(0);
    if (!isW && c0 + 4 < 32) xwrite(c0 + 4, X0);
    BAR();
  }

  // epilogue: bias + store (each wave owns its outputs; no combine).
  // Q,K -> [b][p][64]; V -> [b][64][p]
#pragma unroll
  for (int n = 0; n < 3; ++n) {
    const int dg = h * 96 + wn * 48 + n * 16 + l15;
    const int wi = dg >> 6, dl = dg & 63;
    const float* bsrc = (wi == 0) ? bq : (wi == 1) ? bk : bv;
    const float bias = bsrc[dl];
    const int pl = wm * 16 + l4 * 4;
    f32x4 a = acc[n];
    if (wi < 2) {
      u16* dst = (wi == 0 ? Qo : Ko) + ((size_t)b * 1024 + p0 + pl) * 64 + dl;
#pragma unroll
      for (int r = 0; r < 4; ++r) dst[(size_t)r * 64] = f2bf(a[r] + bias);
    } else {
      ushort4 hh;
      hh.x = f2bf(a[0] + bias); hh.y = f2bf(a[1] + bias);
      hh.z = f2bf(a[2] + bias); hh.w = f2bf(a[3] + bias);
      *(ushort4*)(Vt + ((size_t)b * 64 + dl) * 1024 + p0 + pl) = hh;
    }
  }
#undef BAR
}

// ---------------- Kernel 2: flash attention (no-max softmax, KV-half split) ----------------
// grid 512 = b(16) x qtile(16) x half(2); block 256 (4 waves x 16 q-rows).
__global__ __launch_bounds__(256) void attn_kernel(
    const u16* __restrict__ Qg, const u16* __restrict__ Kg,
    const u16* __restrict__ Vg, float* __restrict__ Po, float* __restrict__ lp)
{
  const int bid = blockIdx.x;
  const int b  = bid >> 5;
  const int qt = (bid >> 1) & 15;
  const int h  = bid & 1;
  const int q0 = qt * 64;
  const int tid = threadIdx.x;
  const int lane = tid & 63;
  const int wid = tid >> 6;
  const int l15 = lane & 15, l4 = lane >> 4;
  const int qb = q0 + wid * 16;

  __shared__ __align__(16) u16 lK[2][128 * 64];   // swz: blk^=(row>>1)&7
  __shared__ __align__(16) u16 lV[2][64 * 128];   // swz: blk^=(row&7)<<1
  __shared__ __align__(16) u16 lP[4][16 * 128];   // swz: blk^=(row&7)<<1

  s16x8 qa[2];
#pragma unroll
  for (int ks = 0; ks < 2; ++ks)
    qa[ks] = *(const s16x8*)(Qg + ((size_t)b * 1024 + qb + l15) * 64 + ks * 32 + l4 * 8);

  float l_run[4];
  f32x4 oacc[4];
#pragma unroll
  for (int r = 0; r < 4; ++r) l_run[r] = 0.f;
#pragma unroll
  for (int n = 0; n < 4; ++n) oacc[n] = (f32x4)(0.0f);

  u16x8 kp[4], vp[4];
  auto load_kv = [&](int kc) {
    const int pk0 = kc * 128;
#pragma unroll
    for (int i = 0; i < 4; ++i) {
      int idx = tid + 256 * i;
      int row = idx >> 3, blk = idx & 7;
      kp[i] = *(const u16x8*)(Kg + ((size_t)b * 1024 + pk0 + row) * 64 + blk * 8);
      int vr = idx >> 4, vbk = idx & 15;
      vp[i] = *(const u16x8*)(Vg + ((size_t)b * 64 + vr) * 1024 + pk0 + vbk * 8);
    }
  };
  auto store_kv = [&](int buf) {
#pragma unroll
    for (int i = 0; i < 4; ++i) {
      int idx = tid + 256 * i;
      int row = idx >> 3, blk = idx & 7;
      *(u16x8*)(&lK[buf][0] + row * 64 + ((blk ^ ((row >> 1) & 7)) << 3)) = kp[i];
      int vr = idx >> 4, vbk = idx & 15;
      *(u16x8*)(&lV[buf][0] + vr * 128 + ((vbk ^ ((vr & 7) << 1)) << 3)) = vp[i];
    }
  };

  const int kc0 = h * 4;
  load_kv(kc0); store_kv(0); __syncthreads();

  const float CEXP = 0.0225422933f;   // log2(e)/64

  for (int ic = 0; ic < 4; ++ic) {
    const int cur = ic & 1;
    if (ic + 1 < 4) load_kv(kc0 + ic + 1);

    f32x4 sacc[8];
#pragma unroll
    for (int n = 0; n < 8; ++n) sacc[n] = (f32x4)(0.0f);
#pragma unroll
    for (int ks = 0; ks < 2; ++ks) {
#pragma unroll
      for (int n = 0; n < 8; ++n) {
        int row = n * 16 + l15;
        s16x8 kv = *(const s16x8*)(&lK[cur][0] + row * 64 +
                     (((ks * 4 + l4) ^ ((row >> 1) & 7)) << 3));
        sacc[n] = __builtin_amdgcn_mfma_f32_16x16x32_bf16(qa[ks], kv, sacc[n], 0, 0, 0);
      }
    }

#pragma unroll
    for (int r = 0; r < 4; ++r) {
      const int prow = l4 * 4 + r;
      float psum = 0.f;
#pragma unroll
      for (int n = 0; n < 8; ++n) {
        float pv = exp2f(sacc[n][r] * CEXP);
        psum += pv;
        int blk = (n * 2 + (l15 >> 3)) ^ ((prow & 7) << 1);
        lP[wid][prow * 128 + blk * 8 + (l15 & 7)] = f2bf(pv);
      }
      psum += __shfl_xor(psum, 1);
      psum += __shfl_xor(psum, 2);
      psum += __shfl_xor(psum, 4);
      psum += __shfl_xor(psum, 8);
      l_run[r] += psum;
    }

#pragma unroll
    for (int ks = 0; ks < 4; ++ks) {
      s16x8 pfr = *(const s16x8*)(&lP[wid][0] + l15 * 128 +
                    (((ks * 4 + l4) ^ ((l15 & 7) << 1)) << 3));
#pragma unroll
      for (int n = 0; n < 4; ++n) {
        int row = n * 16 + l15;
        s16x8 vv = *(const s16x8*)(&lV[cur][0] + row * 128 +
                     (((ks * 4 + l4) ^ ((row & 7) << 1)) << 3));
        oacc[n] = __builtin_amdgcn_mfma_f32_16x16x32_bf16(pfr, vv, oacc[n], 0, 0, 0);
      }
    }

    if (ic + 1 < 4) store_kv(cur ^ 1);
    __syncthreads();
  }

#pragma unroll
  for (int n = 0; n < 4; ++n) {
    const int d = n * 16 + l15;
    float4 o;
    o.x = oacc[n][0]; o.y = oacc[n][1]; o.z = oacc[n][2]; o.w = oacc[n][3];
    *(float4*)(Po + (((size_t)h * 16 + b) * 64 + d) * 1024 + q0 + wid * 16 + l4 * 4) = o;
  }
  if (l15 == 0) {
#pragma unroll
    for (int r = 0; r < 4; ++r)
      lp[((size_t)h * 16 + b) * 1024 + qb + l4 * 4 + r] = l_run[r];
  }
}

// ---------------- Kernel 3: merge halves ----------------
__global__ __launch_bounds__(256) void attn_merge(
    const float* __restrict__ Po, const float* __restrict__ lp, float* __restrict__ out)
{
  const int i = (blockIdx.x * 256 + threadIdx.x) * 4;
  float4 a = *(const float4*)(Po + i);
  float4 c = *(const float4*)(Po + 1048576 + i);
  const int b = i >> 16;
  const int p = i & 1023;
  const float* l0 = lp + b * 1024 + p;
  const float* l1 = lp + 16384 + b * 1024 + p;
  float4 o;
  o.x = (a.x + c.x) / (l0[0] + l1[0]);
  o.y = (a.y + c.y) / (l0[1] + l1[1]);
  o.z = (a.z + c.z) / (l0[2] + l1[2]);
  o.w = (a.w + c.w) / (l0[3] + l1[3]);
  *(float4*)(out + i) = o;
}

extern "C" void kernel_launch(void* const* d_in, const int* in_sizes, int n_in,
                              void* d_out, int out_size, void* d_ws, size_t ws_size,
                              hipStream_t stream) {
  const float* x  = (const float*)d_in[0];
  const float* wq = (const float*)d_in[1];
  const float* bq = (const float*)d_in[2];
  const float* wk = (const float*)d_in[3];
  const float* bk = (const float*)d_in[4];
  const float* wv = (const float*)d_in[5];
  const float* bv = (const float*)d_in[6];
  float* out = (float*)d_out;

  u16* Qo  = (u16*)d_ws;                              // [16][1024][64] bf16
  u16* Ko  = Qo + (size_t)16 * 1024 * 64;             // [16][1024][64] bf16
  u16* Vt  = Ko + (size_t)16 * 1024 * 64;             // [16][64][1024] bf16
  u16* Wpk = Vt + (size_t)16 * 1024 * 64;             // [32][192][64] bf16 prepacked
  float* Po = (float*)(Wpk + (size_t)32 * 192 * 64);  // [2][16][64][1024] f32 partial O
  float* lpart = Po + (size_t)2 * 16 * 64 * 1024;     // [2][16][1024] f32 partial l

  prepack_w<<<192, 256, 0, stream>>>(wq, wk, wv, Wpk);
  qkv_proj<<<512, 512, 0, stream>>>(x, Wpk, bq, bk, bv, Qo, Ko, Vt);
  attn_kernel<<<512, 256, 0, stream>>>(Qo, Ko, Vt, Po, lpart);
  attn_merge<<<1024, 256, 0, stream>>>(Po, lpart, out);
}

// Round 8
// 64.038 us; speedup vs baseline: 1.2560x; 1.2256x over previous
//
#include <hip/hip_runtime.h>

typedef float f32x4 __attribute__((ext_vector_type(4)));
typedef short s16x8 __attribute__((ext_vector_type(8)));
typedef unsigned short u16;
typedef unsigned short u16x8 __attribute__((ext_vector_type(8)));

__device__ __forceinline__ u16 f2bf(float f) {
  unsigned u = __builtin_bit_cast(unsigned, f);
  u += 0x7fffu + ((u >> 16) & 1u);   // RNE
  return (u16)(u >> 16);
}

__device__ __forceinline__ unsigned cvt_pk_bf16(float a, float b) {
  unsigned r;
  asm("v_cvt_pk_bf16_f32 %0, %1, %2" : "=v"(r) : "v"(a), "v"(b));
  return r;   // lo = bf16(a), hi = bf16(b), RNE
}

#define AS1 __attribute__((address_space(1)))
#define AS3 __attribute__((address_space(3)))
#define GLD16(g, l) __builtin_amdgcn_global_load_lds((const AS1 unsigned int*)(g), (AS3 unsigned int*)(l), 16, 0, 0)
#define SBAR() __builtin_amdgcn_sched_barrier(0)

// ---------------- Kernel 0: prepack W -> bf16, chunk-major, swizzled ----------------
__global__ __launch_bounds__(256) void prepack_w(
    const float* __restrict__ wq, const float* __restrict__ wk, const float* __restrict__ wv,
    u16* __restrict__ Wpk)
{
  const int d = blockIdx.x;          // 0..191
  const int t = threadIdx.x;         // kc = t>>3 (0..31), blk = t&7
  const int kc = t >> 3, blk = t & 7;
  const int key = (d >> 1) & 7;
  const float* src = (d < 64) ? (wq + (size_t)d * 2048)
                   : (d < 128) ? (wk + (size_t)(d - 64) * 2048)
                               : (wv + (size_t)(d - 128) * 2048);
  const float* s8 = src + kc * 64 + ((blk ^ key) << 3);
  u16x8 o;
#pragma unroll
  for (int j = 0; j < 8; ++j) o[j] = f2bf(s8[j]);
  *(u16x8*)(Wpk + ((size_t)(kc * 192 + d) << 6) + (blk << 3)) = o;
}

// ---------------- Kernel 1: fused QKV projection, 8 fat intervals ----------------
// grid 256 (16b x 16ptile), block 256 (4 waves). Wave wn owns 64p x 48d (m4 x n3).
// Interval = k:256 (4 chunks). lA dbuf 2x32KB; W: 4 wave-PRIVATE 24KB regions,
// single-buffered, loaded by own GLD16, readiness via counted vmcnt (no barrier).
// One s_barrier per interval (lA handoff). Queue discipline: [W(24), x(16)].
__global__ __launch_bounds__(256) void qkv_proj(
    const float* __restrict__ x, const u16* __restrict__ Wpk,
    const float* __restrict__ bq, const float* __restrict__ bk, const float* __restrict__ bv,
    u16* __restrict__ Qo, u16* __restrict__ Ko, u16* __restrict__ Vt)
{
  const int b   = blockIdx.x >> 4;
  const int p0  = (blockIdx.x & 15) * 64;
  const int tid = threadIdx.x;
  const int lane = tid & 63;
  const int wn  = tid >> 6;            // wave owns d in [wn*48, wn*48+48)
  const int l15 = lane & 15, l4 = lane >> 4;

  __shared__ __align__(16) char smem[163840];
  // lA[buf] : smem + buf*32768; chunk kk at +kk*8192; row p at +p*128; 16B blocks XOR-swz
  // W region: smem + 65536 + wn*24576; chunk kk at +kk*6144; row dd at +dd*128
  char* const myreg = smem + 65536 + wn * 24576;

  const int xpg = (tid & 15) * 4;           // p-col group
  const int xr0 = ((tid >> 4) & 15) * 4;    // 4 k-rows base within chunk
  const float* xb = x + (size_t)b * 2048 * 1024 + p0 + xpg;

  f32x4 acc[4][3];
#pragma unroll
  for (int m = 0; m < 4; ++m)
#pragma unroll
    for (int n = 0; n < 3; ++n) acc[m][n] = (f32x4)(0.0f);

  float4 xr[16];

  auto xissue = [&](int i) {
#pragma unroll
    for (int kk = 0; kk < 4; ++kk) {
      const float* g = xb + (size_t)(i * 256 + kk * 64 + xr0) * 1024;
#pragma unroll
      for (int r = 0; r < 4; ++r) xr[kk * 4 + r] = *(const float4*)(g + r * 1024);
    }
  };
  auto xwrite = [&](int i) {   // xr holds interval-i data -> lA[i&1]
    char* base = smem + (i & 1) * 32768;
#pragma unroll
    for (int kk = 0; kk < 4; ++kk) {
#pragma unroll
      for (int cc = 0; cc < 4; ++cc) {
        int p = xpg + cc;
        unsigned lo = cvt_pk_bf16(xr[kk * 4 + 0][cc], xr[kk * 4 + 1][cc]);
        unsigned hi = cvt_pk_bf16(xr[kk * 4 + 2][cc], xr[kk * 4 + 3][cc]);
        int blk = (xr0 >> 3) ^ ((p >> 1) & 7);
        *(uint2*)(base + kk * 8192 + p * 128 + (blk << 4) + (xr0 & 7) * 2) = make_uint2(lo, hi);
      }
    }
  };
  auto wissue = [&](int i) {   // 24 GLD16 into my private region
#pragma unroll
    for (int kk = 0; kk < 4; ++kk) {
      const u16* g = Wpk + ((size_t)((i * 4 + kk) * 192 + wn * 48)) * 64 + lane * 8;
      char* d = myreg + kk * 6144;
#pragma unroll
      for (int q = 0; q < 6; ++q)
        GLD16(g + q * 512, d + q * 1024);
    }
  };
  auto domfma = [&](int buf) {
    const char* aB = smem + buf * 32768;
#pragma unroll
    for (int kk = 0; kk < 4; ++kk) {
      const char* bB = myreg + kk * 6144;
#pragma unroll
      for (int ks = 0; ks < 2; ++ks) {
        s16x8 af[4], bfv[3];
#pragma unroll
        for (int m = 0; m < 4; ++m) {
          int p = m * 16 + l15;
          af[m] = *(const s16x8*)(aB + kk * 8192 + p * 128 +
                    ((((ks * 4 + l4) ^ ((p >> 1) & 7)) & 7) << 4));
        }
#pragma unroll
        for (int n = 0; n < 3; ++n) {
          int dd = n * 16 + l15;            // key((wn*48+dd)>>1 &7) == key(dd>>1 &7)
          bfv[n] = *(const s16x8*)(bB + dd * 128 +
                     ((((ks * 4 + l4) ^ ((dd >> 1) & 7)) & 7) << 4));
        }
#pragma unroll
        for (int m = 0; m < 4; ++m)
#pragma unroll
          for (int n = 0; n < 3; ++n)
            acc[m][n] = __builtin_amdgcn_mfma_f32_16x16x32_bf16(af[m], bfv[n], acc[m][n], 0, 0, 0);
      }
    }
  };

  // prologue: queue ends as [W0(24), x1(16)]
  xissue(0);
  SBAR();
  wissue(0);
  SBAR();
  xwrite(0);                 // compiler auto-waits x0 (vmcnt<=24)
  SBAR();
  xissue(1);
  asm volatile("s_waitcnt lgkmcnt(0)" ::: "memory");
  SBAR();
  __builtin_amdgcn_s_barrier();
  SBAR();

  for (int i = 0; i < 8; ++i) {
    // entry queue: [W_i(24), x_{i+1}(16)]  (i==7: [W_7(24)] only)
    if (i < 7) asm volatile("s_waitcnt vmcnt(16)" ::: "memory");
    else       asm volatile("s_waitcnt vmcnt(0)"  ::: "memory");
    SBAR();
    domfma(i & 1);
    if (i < 7) {
      asm volatile("s_waitcnt lgkmcnt(0)" ::: "memory");  // my region reads retired
      SBAR();
      wissue(i + 1);          // overwrite own region (safe: own reads done)
      SBAR();
      xwrite(i + 1);          // auto-waits x_{i+1} (vmcnt<=24), W_{i+1} stays in flight
      SBAR();
      if (i + 2 < 8) xissue(i + 2);
      asm volatile("s_waitcnt lgkmcnt(0)" ::: "memory");  // lA writes visible
      SBAR();
      __builtin_amdgcn_s_barrier();
      SBAR();
    }
  }

  // epilogue: bias + store. Q,K -> [b][p][64]; V -> [b][64][p]
#pragma unroll
  for (int n = 0; n < 3; ++n) {
    const int dg = wn * 48 + n * 16 + l15;
    const int wi = dg >> 6, dl = dg & 63;
    const float* bsrc = (wi == 0) ? bq : (wi == 1) ? bk : bv;
    const float bias = bsrc[dl];
#pragma unroll
    for (int m = 0; m < 4; ++m) {
      const int pl = m * 16 + l4 * 4;
      f32x4 a = acc[m][n];
      if (wi < 2) {
        u16* dst = (wi == 0 ? Qo : Ko) + ((size_t)b * 1024 + p0 + pl) * 64 + dl;
#pragma unroll
        for (int r = 0; r < 4; ++r) dst[(size_t)r * 64] = f2bf(a[r] + bias);
      } else {
        ushort4 hh;
        hh.x = f2bf(a[0] + bias); hh.y = f2bf(a[1] + bias);
        hh.z = f2bf(a[2] + bias); hh.w = f2bf(a[3] + bias);
        *(ushort4*)(Vt + ((size_t)b * 64 + dl) * 1024 + p0 + pl) = hh;
      }
    }
  }
}

// ---------------- Kernel 2: flash attention (no-max softmax, KV-half split) ----------------
// grid 512 = b(16) x qtile(16) x half(2); block 256 (4 waves x 16 q-rows).
__global__ __launch_bounds__(256) void attn_kernel(
    const u16* __restrict__ Qg, const u16* __restrict__ Kg,
    const u16* __restrict__ Vg, float* __restrict__ Po, float* __restrict__ lp)
{
  const int bid = blockIdx.x;
  const int b  = bid >> 5;
  const int qt = (bid >> 1) & 15;
  const int h  = bid & 1;
  const int q0 = qt * 64;
  const int tid = threadIdx.x;
  const int lane = tid & 63;
  const int wid = tid >> 6;
  const int l15 = lane & 15, l4 = lane >> 4;
  const int qb = q0 + wid * 16;

  __shared__ __align__(16) u16 lK[2][128 * 64];   // swz: blk^=(row>>1)&7
  __shared__ __align__(16) u16 lV[2][64 * 128];   // swz: blk^=(row&7)<<1
  __shared__ __align__(16) u16 lP[4][16 * 128];   // swz: blk^=(row&7)<<1

  s16x8 qa[2];
#pragma unroll
  for (int ks = 0; ks < 2; ++ks)
    qa[ks] = *(const s16x8*)(Qg + ((size_t)b * 1024 + qb + l15) * 64 + ks * 32 + l4 * 8);

  float l_run[4];
  f32x4 oacc[4];
#pragma unroll
  for (int r = 0; r < 4; ++r) l_run[r] = 0.f;
#pragma unroll
  for (int n = 0; n < 4; ++n) oacc[n] = (f32x4)(0.0f);

  u16x8 kp[4], vp[4];
  auto load_kv = [&](int kc) {
    const int pk0 = kc * 128;
#pragma unroll
    for (int i = 0; i < 4; ++i) {
      int idx = tid + 256 * i;
      int row = idx >> 3, blk = idx & 7;
      kp[i] = *(const u16x8*)(Kg + ((size_t)b * 1024 + pk0 + row) * 64 + blk * 8);
      int vr = idx >> 4, vbk = idx & 15;
      vp[i] = *(const u16x8*)(Vg + ((size_t)b * 64 + vr) * 1024 + pk0 + vbk * 8);
    }
  };
  auto store_kv = [&](int buf) {
#pragma unroll
    for (int i = 0; i < 4; ++i) {
      int idx = tid + 256 * i;
      int row = idx >> 3, blk = idx & 7;
      *(u16x8*)(&lK[buf][0] + row * 64 + ((blk ^ ((row >> 1) & 7)) << 3)) = kp[i];
      int vr = idx >> 4, vbk = idx & 15;
      *(u16x8*)(&lV[buf][0] + vr * 128 + ((vbk ^ ((vr & 7) << 1)) << 3)) = vp[i];
    }
  };

  const int kc0 = h * 4;
  load_kv(kc0); store_kv(0); __syncthreads();

  const float CEXP = 0.0225422933f;   // log2(e)/64

  for (int ic = 0; ic < 4; ++ic) {
    const int cur = ic & 1;
    if (ic + 1 < 4) load_kv(kc0 + ic + 1);

    f32x4 sacc[8];
#pragma unroll
    for (int n = 0; n < 8; ++n) sacc[n] = (f32x4)(0.0f);
#pragma unroll
    for (int ks = 0; ks < 2; ++ks) {
#pragma unroll
      for (int n = 0; n < 8; ++n) {
        int row = n * 16 + l15;
        s16x8 kv = *(const s16x8*)(&lK[cur][0] + row * 64 +
                     (((ks * 4 + l4) ^ ((row >> 1) & 7)) << 3));
        sacc[n] = __builtin_amdgcn_mfma_f32_16x16x32_bf16(qa[ks], kv, sacc[n], 0, 0, 0);
      }
    }

#pragma unroll
    for (int r = 0; r < 4; ++r) {
      const int prow = l4 * 4 + r;
      float psum = 0.f;
#pragma unroll
      for (int n = 0; n < 8; ++n) {
        float pv = exp2f(sacc[n][r] * CEXP);
        psum += pv;
        int blk = (n * 2 + (l15 >> 3)) ^ ((prow & 7) << 1);
        lP[wid][prow * 128 + blk * 8 + (l15 & 7)] = f2bf(pv);
      }
      psum += __shfl_xor(psum, 1);
      psum += __shfl_xor(psum, 2);
      psum += __shfl_xor(psum, 4);
      psum += __shfl_xor(psum, 8);
      l_run[r] += psum;
    }

#pragma unroll
    for (int ks = 0; ks < 4; ++ks) {
      s16x8 pfr = *(const s16x8*)(&lP[wid][0] + l15 * 128 +
                    (((ks * 4 + l4) ^ ((l15 & 7) << 1)) << 3));
#pragma unroll
      for (int n = 0; n < 4; ++n) {
        int row = n * 16 + l15;
        s16x8 vv = *(const s16x8*)(&lV[cur][0] + row * 128 +
                     (((ks * 4 + l4) ^ ((row & 7) << 1)) << 3));
        oacc[n] = __builtin_amdgcn_mfma_f32_16x16x32_bf16(pfr, vv, oacc[n], 0, 0, 0);
      }
    }

    if (ic + 1 < 4) store_kv(cur ^ 1);
    __syncthreads();
  }

#pragma unroll
  for (int n = 0; n < 4; ++n) {
    const int d = n * 16 + l15;
    float4 o;
    o.x = oacc[n][0]; o.y = oacc[n][1]; o.z = oacc[n][2]; o.w = oacc[n][3];
    *(float4*)(Po + (((size_t)h * 16 + b) * 64 + d) * 1024 + q0 + wid * 16 + l4 * 4) = o;
  }
  if (l15 == 0) {
#pragma unroll
    for (int r = 0; r < 4; ++r)
      lp[((size_t)h * 16 + b) * 1024 + qb + l4 * 4 + r] = l_run[r];
  }
}

// ---------------- Kernel 3: merge halves ----------------
__global__ __launch_bounds__(256) void attn_merge(
    const float* __restrict__ Po, const float* __restrict__ lp, float* __restrict__ out)
{
  const int i = (blockIdx.x * 256 + threadIdx.x) * 4;
  float4 a = *(const float4*)(Po + i);
  float4 c = *(const float4*)(Po + 1048576 + i);
  const int b = i >> 16;
  const int p = i & 1023;
  const float* l0 = lp + b * 1024 + p;
  const float* l1 = lp + 16384 + b * 1024 + p;
  float4 o;
  o.x = (a.x + c.x) / (l0[0] + l1[0]);
  o.y = (a.y + c.y) / (l0[1] + l1[1]);
  o.z = (a.z + c.z) / (l0[2] + l1[2]);
  o.w = (a.w + c.w) / (l0[3] + l1[3]);
  *(float4*)(out + i) = o;
}

extern "C" void kernel_launch(void* const* d_in, const int* in_sizes, int n_in,
                              void* d_out, int out_size, void* d_ws, size_t ws_size,
                              hipStream_t stream) {
  const float* x  = (const float*)d_in[0];
  const float* wq = (const float*)d_in[1];
  const float* bq = (const float*)d_in[2];
  const float* wk = (const float*)d_in[3];
  const float* bk = (const float*)d_in[4];
  const float* wv = (const float*)d_in[5];
  const float* bv = (const float*)d_in[6];
  float* out = (float*)d_out;

  u16* Qo  = (u16*)d_ws;                              // [16][1024][64] bf16
  u16* Ko  = Qo + (size_t)16 * 1024 * 64;             // [16][1024][64] bf16
  u16* Vt  = Ko + (size_t)16 * 1024 * 64;             // [16][64][1024] bf16
  u16* Wpk = Vt + (size_t)16 * 1024 * 64;             // [32][192][64] bf16 prepacked
  float* Po = (float*)(Wpk + (size_t)32 * 192 * 64);  // [2][16][64][1024] f32 partial O
  float* lpart = Po + (size_t)2 * 16 * 64 * 1024;     // [2][16][1024] f32 partial l

  prepack_w<<<192, 256, 0, stream>>>(wq, wk, wv, Wpk);
  qkv_proj<<<256, 256, 0, stream>>>(x, Wpk, bq, bk, bv, Qo, Ko, Vt);
  attn_kernel<<<512, 256, 0, stream>>>(Qo, Ko, Vt, Po, lpart);
  attn_merge<<<1024, 256, 0, stream>>>(Po, lpart, out);
}